// Round 3
// baseline (1901.590 us; speedup 1.0000x reference)
//
#include <hip/hip_runtime.h>

#define SEQ 128
#define BSZ 64
#define EMB 32
#define HD  8
#define VOC 32000
#define P   8    // positions per block in output kernel

typedef float f32x4 __attribute__((ext_vector_type(4)));

// ---------------------------------------------------------------------------
// Kernel 0: xproj[s][b][h] = lookup[idx[s,b]] @ Wx + b1 + b2, both directions.
// Stored transposed per-thread-contiguous: xpf[(b*8+h)*SEQ + s].
// Backward copy is stored TIME-REVERSED so the scan always walks t=0..127.
// ---------------------------------------------------------------------------
__global__ __launch_bounds__(256) void xproj_kernel(
    const int*   __restrict__ idx,
    const float* __restrict__ lookup,
    const float* __restrict__ Wxf, const float* __restrict__ Wxb,
    const float* __restrict__ bf1, const float* __restrict__ bf2,
    const float* __restrict__ bb1, const float* __restrict__ bb2,
    float* __restrict__ xpf, float* __restrict__ xpb)
{
    const int i = blockIdx.x * 256 + threadIdx.x;   // flat (s*B + b)
    if (i >= SEQ * BSZ) return;
    const int s = i >> 6;          // / BSZ
    const int b = i & 63;          // % BSZ

    const float* xr = lookup + (size_t)idx[i] * EMB;
    float x[EMB];
#pragma unroll
    for (int e = 0; e < EMB; ++e) x[e] = xr[e];

#pragma unroll
    for (int h = 0; h < HD; ++h) {
        float af = bf1[h] + bf2[h];
        float ab = bb1[h] + bb2[h];
#pragma unroll
        for (int e = 0; e < EMB; ++e) {
            af = fmaf(x[e], Wxf[e * HD + h], af);
            ab = fmaf(x[e], Wxb[e * HD + h], ab);
        }
        xpf[(b * HD + h) * SEQ + s]             = af;
        xpb[(b * HD + h) * SEQ + (SEQ - 1 - s)] = ab;   // time-reversed
    }
}

// ---------------------------------------------------------------------------
// Kernel 1: the serial recurrence, pure-register.
// grid = 2 (dir), 512 threads = 64 batch x 8 hidden. Each thread preloads its
// 128 xproj values (32 float4) then runs a fully-unrolled 128-step scan:
// 8 shfl + 8 fma + fast tanh per step. Writes PREVIOUS state (lax.scan).
// ---------------------------------------------------------------------------
__global__ __launch_bounds__(512) void rnn_scan_kernel(
    const float* __restrict__ xpf, const float* __restrict__ xpb,
    const float* __restrict__ Whf, const float* __restrict__ Whb,
    const float* __restrict__ Hf0, const float* __restrict__ Hb0,
    float* __restrict__ Hcat)
{
    const int dir = blockIdx.x;
    const int tid = threadIdx.x;
    const int b   = tid >> 3;
    const int h   = tid & 7;

    const float* Wh = dir ? Whb : Whf;
    const float* xp = (dir ? xpb : xpf) + (size_t)tid * SEQ;

    float wh[HD];
#pragma unroll
    for (int j = 0; j < HD; ++j) wh[j] = Wh[j * HD + h];

    float xs[SEQ];
    const f32x4* xp4 = (const f32x4*)xp;
#pragma unroll
    for (int q = 0; q < SEQ / 4; ++q) {
        f32x4 v = xp4[q];
        xs[4 * q + 0] = v.x; xs[4 * q + 1] = v.y;
        xs[4 * q + 2] = v.z; xs[4 * q + 3] = v.w;
    }

    float hcur = dir ? Hb0[h] : Hf0[h];
    const int koff = dir ? HD : 0;

#pragma unroll
    for (int t = 0; t < SEQ; ++t) {
        const int s = dir ? (SEQ - 1 - t) : t;
        Hcat[(s * BSZ + b) * 16 + koff + h] = hcur;   // previous state

        float acc = xs[t];                            // static index
#pragma unroll
        for (int j = 0; j < HD; ++j)
            acc = fmaf(__shfl(hcur, j, 8), wh[j], acc);

        // tanh via exp; |acc| is bounded (~<6) so no overflow.
        float e = __expf(2.0f * acc);
        hcur = (e - 1.0f) / (e + 1.0f);
    }
}

// ---------------------------------------------------------------------------
// Kernel 2: logits = Hcat @ Wo + bo, log_softmax over V.
// grid = 1024 blocks x 256 threads; block owns P=8 positions x all V.
// Nontemporal output stores keep Wo resident in L2. launch_bounds(256,4)
// caps VGPRs at 128 -> 4 waves/SIMD.
// ---------------------------------------------------------------------------
__global__ __launch_bounds__(256, 4) void out_softmax_kernel(
    const float* __restrict__ Hcat,
    const float* __restrict__ Wo,
    const float* __restrict__ bo,
    float* __restrict__ out)
{
    __shared__ float hls[P][16];
    __shared__ float red[4][P];
    __shared__ float lsum[P];

    const int tid = threadIdx.x;
    const int pb  = blockIdx.x;

    if (tid < P * 16) hls[tid >> 4][tid & 15] = Hcat[pb * (P * 16) + tid];
    __syncthreads();

    float sacc[P];
#pragma unroll
    for (int p = 0; p < P; ++p) sacc[p] = 0.f;

    // ---- pass 1: sum of exp(logit); |logit| <= ~0.2 so max-subtract skipped
    for (int c = 0; c < 31; ++c) {
        const int v = c * 1024 + tid * 4;
        f32x4 bo4 = *(const f32x4*)(bo + v);
        f32x4 wo[16];
#pragma unroll
        for (int k = 0; k < 16; ++k) wo[k] = *(const f32x4*)(Wo + k * VOC + v);
#pragma unroll
        for (int p = 0; p < P; ++p) {
            f32x4 lg = bo4;
#pragma unroll
            for (int k = 0; k < 16; ++k) {
                const float hv = hls[p][k];
                lg.x = fmaf(hv, wo[k].x, lg.x);
                lg.y = fmaf(hv, wo[k].y, lg.y);
                lg.z = fmaf(hv, wo[k].z, lg.z);
                lg.w = fmaf(hv, wo[k].w, lg.w);
            }
            sacc[p] += __expf(lg.x) + __expf(lg.y) + __expf(lg.z) + __expf(lg.w);
        }
    }
    {   // remainder: v = 31744 + tid
        const int v = 31744 + tid;
        const float bos = bo[v];
        float woS[16];
#pragma unroll
        for (int k = 0; k < 16; ++k) woS[k] = Wo[k * VOC + v];
#pragma unroll
        for (int p = 0; p < P; ++p) {
            float lg = bos;
#pragma unroll
            for (int k = 0; k < 16; ++k) lg = fmaf(hls[p][k], woS[k], lg);
            sacc[p] += __expf(lg);
        }
    }

    // ---- block reduction ----
    const int lane = tid & 63;
    const int wv   = tid >> 6;
#pragma unroll
    for (int p = 0; p < P; ++p) {
        float s = sacc[p];
#pragma unroll
        for (int off = 32; off > 0; off >>= 1) s += __shfl_xor(s, off, 64);
        if (lane == 0) red[wv][p] = s;
    }
    __syncthreads();
    if (tid < P)
        lsum[tid] = logf(red[0][tid] + red[1][tid] + red[2][tid] + red[3][tid]);
    __syncthreads();

    float lsr[P];
#pragma unroll
    for (int p = 0; p < P; ++p) lsr[p] = lsum[p];

    // ---- pass 2: recompute logits, nontemporal write of log_softmax ----
    const size_t obase = (size_t)pb * P * VOC;
    for (int c = 0; c < 31; ++c) {
        const int v = c * 1024 + tid * 4;
        f32x4 bo4 = *(const f32x4*)(bo + v);
        f32x4 wo[16];
#pragma unroll
        for (int k = 0; k < 16; ++k) wo[k] = *(const f32x4*)(Wo + k * VOC + v);
#pragma unroll
        for (int p = 0; p < P; ++p) {
            f32x4 lg = bo4;
#pragma unroll
            for (int k = 0; k < 16; ++k) {
                const float hv = hls[p][k];
                lg.x = fmaf(hv, wo[k].x, lg.x);
                lg.y = fmaf(hv, wo[k].y, lg.y);
                lg.z = fmaf(hv, wo[k].z, lg.z);
                lg.w = fmaf(hv, wo[k].w, lg.w);
            }
            f32x4 o;
            o.x = lg.x - lsr[p]; o.y = lg.y - lsr[p];
            o.z = lg.z - lsr[p]; o.w = lg.w - lsr[p];
            __builtin_nontemporal_store(o, (f32x4*)(out + obase + (size_t)p * VOC + v));
        }
    }
    {   // remainder
        const int v = 31744 + tid;
        const float bos = bo[v];
        float woS[16];
#pragma unroll
        for (int k = 0; k < 16; ++k) woS[k] = Wo[k * VOC + v];
#pragma unroll
        for (int p = 0; p < P; ++p) {
            float lg = bos;
#pragma unroll
            for (int k = 0; k < 16; ++k) lg = fmaf(hls[p][k], woS[k], lg);
            __builtin_nontemporal_store(lg - lsr[p], out + obase + (size_t)p * VOC + v);
        }
    }
}

extern "C" void kernel_launch(void* const* d_in, const int* in_sizes, int n_in,
                              void* d_out, int out_size, void* d_ws, size_t ws_size,
                              hipStream_t stream)
{
    const int*   idx    = (const int*)  d_in[0];
    const float* lookup = (const float*)d_in[1];
    const float* Wxf    = (const float*)d_in[2];
    const float* Whf    = (const float*)d_in[3];
    const float* Wxb    = (const float*)d_in[4];
    const float* Whb    = (const float*)d_in[5];
    const float* Wo     = (const float*)d_in[6];
    const float* Hf0    = (const float*)d_in[7];
    const float* Hb0    = (const float*)d_in[8];
    const float* bf1    = (const float*)d_in[9];
    const float* bf2    = (const float*)d_in[10];
    const float* bb1    = (const float*)d_in[11];
    const float* bb2    = (const float*)d_in[12];
    const float* bo     = (const float*)d_in[13];
    float* out = (float*)d_out;

    float* Hcat = (float*)d_ws;                       // 8192*16 f32 = 512 KB
    float* xpf  = Hcat + SEQ * BSZ * 16;              // 64*8*128 f32 = 256 KB
    float* xpb  = xpf + BSZ * HD * SEQ;               // 256 KB

    hipLaunchKernelGGL(xproj_kernel, dim3(SEQ * BSZ / 256), dim3(256), 0, stream,
                       idx, lookup, Wxf, Wxb, bf1, bf2, bb1, bb2, xpf, xpb);
    hipLaunchKernelGGL(rnn_scan_kernel, dim3(2), dim3(512), 0, stream,
                       xpf, xpb, Whf, Whb, Hf0, Hb0, Hcat);
    hipLaunchKernelGGL(out_softmax_kernel, dim3(SEQ * BSZ / P), dim3(256), 0, stream,
                       Hcat, Wo, bo, out);
}